// Round 1
// baseline (272.814 us; speedup 1.0000x reference)
//
#include <hip/hip_runtime.h>
#include <math.h>

// ConvBertLightConv: dynamic depthwise conv with softmax-normalized per-(pos,head) kernels.
// B=8, S=4096, D=768 (12 heads x 64), K=9, 'same' zero padding along S.
// out[b,s,h,d] = sum_k softmax(filters[b,s,h,:])[k] * x[b, s+k-4, h*64+d]

#define KS 9
#define HD 64
#define NH 12
#define DMODEL 768   // NH*HD
#define SEQ 4096
#define BATCH 8

__global__ __launch_bounds__(192) void lightconv_kernel(
    const float* __restrict__ x,      // [B, S, 768]
    const float* __restrict__ filt,   // [B, S, 108]
    float* __restrict__ out)          // [B, S, 768]
{
    const int bs = blockIdx.x;            // b*SEQ + s
    const int s  = bs & (SEQ - 1);
    const int t  = threadIdx.x;           // 0..191
    const int head = t >> 4;              // 0..11
    const int d4   = (t & 15) << 2;       // 0,4,...,60

    // --- per-(b,s,head) softmax over the 9 taps (redundant across 16 threads; L1 broadcast) ---
    const float* fp = filt + (size_t)bs * (NH * KS) + head * KS;
    float w[KS];
    float m = -1e30f;
#pragma unroll
    for (int k = 0; k < KS; ++k) { w[k] = fp[k]; m = fmaxf(m, w[k]); }
    float sum = 0.f;
#pragma unroll
    for (int k = 0; k < KS; ++k) { w[k] = __expf(w[k] - m); sum += w[k]; }
    const float inv = 1.0f / sum;

    // --- 9-tap conv, float4 per thread ---
    const size_t rowbase = (size_t)bs * DMODEL + head * HD + d4;
    float4 acc = make_float4(0.f, 0.f, 0.f, 0.f);
#pragma unroll
    for (int k = 0; k < KS; ++k) {
        const int ss = s + k - (KS / 2);
        if (ss >= 0 && ss < SEQ) {
            const float4 v =
                *reinterpret_cast<const float4*>(x + rowbase + (ptrdiff_t)(k - KS / 2) * DMODEL);
            acc.x += w[k] * v.x;
            acc.y += w[k] * v.y;
            acc.z += w[k] * v.z;
            acc.w += w[k] * v.w;
        }
    }
    acc.x *= inv; acc.y *= inv; acc.z *= inv; acc.w *= inv;
    *reinterpret_cast<float4*>(out + rowbase) = acc;
}

extern "C" void kernel_launch(void* const* d_in, const int* in_sizes, int n_in,
                              void* d_out, int out_size, void* d_ws, size_t ws_size,
                              hipStream_t stream) {
    const float* x    = (const float*)d_in[0];   // [8,4096,768] fp32
    const float* filt = (const float*)d_in[1];   // [8,4096,108] fp32
    float* out        = (float*)d_out;           // [8,4096,12,64] fp32

    const int grid = BATCH * SEQ;                // one block per (b,s)
    lightconv_kernel<<<grid, 192, 0, stream>>>(x, filt, out);
}

// Round 2
// 198.684 us; speedup vs baseline: 1.3731x; 1.3731x over previous
//
#include <hip/hip_runtime.h>
#include <math.h>

// ConvBertLightConv: dynamic depthwise conv with softmax-normalized per-(pos,head) kernels.
// B=8, S=4096, D=768 (12 heads x 64), K=9, 'same' zero padding along S.
// out[b,s,h,d] = sum_k softmax(filters[b,s,h,:])[k] * x[b, s+k-4, h*64+d]
//
// R2: sliding-window register reuse. Block = (b, 32 consecutive s), 192 threads
// = 12 heads x 16 float4 columns. 9-row window lives in registers; one new row
// load per position -> x fetched ~1.25x instead of the R1 ~4x (cross-XCD halo
// re-fetch). Full unroll so the compiler pipelines next-row loads over compute.

#define KS 9
#define HD 64
#define NH 12
#define DMODEL 768   // NH*HD
#define SEQ 4096
#define BATCH 8
#define TTILE 32     // s-positions per block
#define CHUNKS (SEQ / TTILE)

__global__ __launch_bounds__(192, 4) void lightconv_kernel(
    const float* __restrict__ x,      // [B, S, 768]
    const float* __restrict__ filt,   // [B, S, 108]
    float* __restrict__ out)          // [B, S, 768]
{
    const int blk   = blockIdx.x;             // b * CHUNKS + chunk
    const int chunk = blk & (CHUNKS - 1);
    const int b     = blk / CHUNKS;
    const int s0    = chunk * TTILE;
    const int t     = threadIdx.x;            // 0..191
    const int head  = t >> 4;                 // 0..11
    const int d4    = (t & 15) << 2;          // 0,4,...,60

    // column base: x[b, 0, head*64 + d4]
    const float*  xc = x   + (size_t)b * SEQ * DMODEL + head * HD + d4;
    float*        oc = out + (size_t)b * SEQ * DMODEL + head * HD + d4;
    const float*  fc = filt + (size_t)b * SEQ * (NH * KS) + head * KS;

    const float4 zero = make_float4(0.f, 0.f, 0.f, 0.f);

    // preload window rows s0-4 .. s0+3  (win[8] filled per-iteration)
    float4 win[KS];
#pragma unroll
    for (int k = 0; k < KS - 1; ++k) {
        const int ss = s0 + k - (KS / 2);
        win[k] = (ss >= 0) ? *reinterpret_cast<const float4*>(xc + (size_t)ss * DMODEL) : zero;
    }

#pragma unroll
    for (int i = 0; i < TTILE; ++i) {
        const int s  = s0 + i;
        const int ss = s + (KS / 2);          // new trailing row
        win[KS - 1] = (ss < SEQ) ? *reinterpret_cast<const float4*>(xc + (size_t)ss * DMODEL)
                                 : zero;

        // softmax over 9 taps for (b, s, head) — redundant across the 16
        // threads of a head; L1-broadcast served.
        const float* fp = fc + (size_t)s * (NH * KS);
        float w[KS];
        float m = -1e30f;
#pragma unroll
        for (int k = 0; k < KS; ++k) { w[k] = fp[k]; m = fmaxf(m, w[k]); }
        float sum = 0.f;
#pragma unroll
        for (int k = 0; k < KS; ++k) { w[k] = __expf(w[k] - m); sum += w[k]; }
        const float inv = 1.0f / sum;

        float4 acc = zero;
#pragma unroll
        for (int k = 0; k < KS; ++k) {
            const float wk = w[k] * inv;
            acc.x += wk * win[k].x;
            acc.y += wk * win[k].y;
            acc.z += wk * win[k].z;
            acc.w += wk * win[k].w;
        }
        *reinterpret_cast<float4*>(oc + (size_t)s * DMODEL) = acc;

        // rotate window (register renaming after full unroll)
#pragma unroll
        for (int k = 0; k < KS - 1; ++k) win[k] = win[k + 1];
    }
}

extern "C" void kernel_launch(void* const* d_in, const int* in_sizes, int n_in,
                              void* d_out, int out_size, void* d_ws, size_t ws_size,
                              hipStream_t stream) {
    const float* x    = (const float*)d_in[0];   // [8,4096,768] fp32
    const float* filt = (const float*)d_in[1];   // [8,4096,108] fp32
    float* out        = (float*)d_out;           // [8,4096,12,64] fp32

    const int grid = BATCH * CHUNKS;             // 8 * 128 = 1024 blocks
    lightconv_kernel<<<grid, 192, 0, stream>>>(x, filt, out);
}